// Round 13
// baseline (146.987 us; speedup 1.0000x reference)
//
#include <hip/hip_runtime.h>
#include <math.h>

#define FF 2048

typedef __attribute__((ext_vector_type(8))) short short8;
typedef __attribute__((ext_vector_type(4))) float floatx4;

// ws float offsets (split-K: 8/8/8/16)
#define OFF_SPART 0                      // [8][64][1000]
#define OFF_HPART 512000                 // [8][64][1000]
#define OFF_SELP  1024000                // [8][64][2048]
#define OFF_MEMP  2072576                // [8][64][2048]
#define OFF_LOGP  3121152                // [16][64][1000]
#define OFF_HROW  4145152                // [64][1024]
#define OFF_FEAT  4210688                // [64][2048]
#define OFF_CN2   4341760                // [1000]
#define OFF_WINV  4342760                // [1000]
#define OFF_XN2   4343760                // [64]
#define OFF_MM    4343824                // [64][8][4] (min,max,sumexp,-)
#define OFF_ROWF  4345872                // [64][4] (gmax, invden, reach,-)
#define OFF_NRM2P 4346128                // [64][8]
#define OFF_CTR   4346640                // 64 counters x 16-dword stride
#define OFF_FLAG  4347664                // release flags x 16-dword stride

#define TP 40   // LDS tile pitch in shorts: 32 data + 8 pad

// ---- coherent scalar ops (LLC): global_*_dword sc0 sc1
__device__ __forceinline__ float cld(const float* p) {
  return __hip_atomic_load(p, __ATOMIC_RELAXED, __HIP_MEMORY_SCOPE_AGENT);
}
__device__ __forceinline__ void cst(float* p, float v) {
  __hip_atomic_store(p, v, __ATOMIC_RELAXED, __HIP_MEMORY_SCOPE_AGENT);
}
// ---- coherent vector ops via inline asm (floatx4 = ext_vector -> VGPR quad)
__device__ __forceinline__ floatx4 cld4(const float* p) {
  floatx4 d;
  asm volatile("global_load_dwordx4 %0, %1, off sc0 sc1\n\ts_waitcnt vmcnt(0)"
               : "=&v"(d) : "v"(p) : "memory");
  return d;
}
__device__ __forceinline__ void cld4x2(const float* p0, const float* p1,
                                       floatx4& a, floatx4& b) {
  asm volatile(
      "global_load_dwordx4 %0, %2, off sc0 sc1\n\t"
      "global_load_dwordx4 %1, %3, off sc0 sc1\n\t"
      "s_waitcnt vmcnt(0)"
      : "=&v"(a), "=&v"(b)
      : "v"(p0), "v"(p1)
      : "memory");
}
__device__ __forceinline__ void cld4x4(const float* p0, const float* p1,
                                       const float* p2, const float* p3,
                                       floatx4& a, floatx4& b, floatx4& c, floatx4& d) {
  asm volatile(
      "global_load_dwordx4 %0, %4, off sc0 sc1\n\t"
      "global_load_dwordx4 %1, %5, off sc0 sc1\n\t"
      "global_load_dwordx4 %2, %6, off sc0 sc1\n\t"
      "global_load_dwordx4 %3, %7, off sc0 sc1\n\t"
      "s_waitcnt vmcnt(0)"
      : "=&v"(a), "=&v"(b), "=&v"(c), "=&v"(d)
      : "v"(p0), "v"(p1), "v"(p2), "v"(p3)
      : "memory");
}
__device__ __forceinline__ void cst4(float* p, floatx4 v) {
  asm volatile("global_store_dwordx4 %0, %1, off sc0 sc1" :: "v"(p), "v"(v) : "memory");
}

__device__ __forceinline__ void split2(float f, ushort& h, ushort& l) {
  unsigned u = __float_as_uint(f);
  float r = f - __uint_as_float(u & 0xffff0000u);
  h = (ushort)(u >> 16);
  l = (ushort)(__float_as_uint(r) >> 16);
}

// Stage 64 rows x 32 k of row-major-K INPUT matrix (cached loads) into hi/lo bf16 LDS [64][TP].
__device__ __forceinline__ void stage_bt_bf(const float* __restrict__ M, int ldK, int rowBase,
                                            int nrows, int k0, int kmax,
                                            ushort* __restrict__ hi, ushort* __restrict__ lo, int t) {
  int r = t >> 2, q = t & 3;
  int grow = rowBase + r;
  bool rok = grow < nrows;
  const float* src = M + (size_t)grow * ldK + k0 + q * 8;
#pragma unroll
  for (int h = 0; h < 2; ++h) {
    int kb = k0 + q * 8 + h * 4;
    float4 v = make_float4(0.f, 0.f, 0.f, 0.f);
    if (rok) {
      if (kb + 3 < kmax) {
        v = *(const float4*)(src + h * 4);
      } else {
#pragma unroll
        for (int j = 0; j < 4; ++j)
          if (kb + j < kmax) ((float*)&v)[j] = src[h * 4 + j];
      }
    }
    ushort4 hv, lv;
    split2(v.x, hv.x, lv.x); split2(v.y, hv.y, lv.y);
    split2(v.z, hv.z, lv.z); split2(v.w, hv.w, lv.w);
    int base = r * TP + q * 8 + h * 4;
    *(ushort4*)(hi + base) = hv;
    *(ushort4*)(lo + base) = lv;
  }
}

// Stage V-tile for phase C from Hrow: V[r][kk] = exp(Hrow - gmax_r) * invden_r (kk<1000)
__device__ __forceinline__ void stage_v(const float* __restrict__ hrowg, float gm, float inv,
                                        int k0, ushort* __restrict__ hi, ushort* __restrict__ lo, int t) {
  int r = t >> 2, q = t & 3;
#pragma unroll
  for (int h = 0; h < 2; ++h) {
    int kb = k0 + q * 8 + h * 4;
    floatx4 hv4 = cld4(hrowg + (size_t)r * 1024 + kb);
    float v[4];
#pragma unroll
    for (int j = 0; j < 4; ++j)
      v[j] = (kb + j < 1000) ? expf(hv4[j] - gm) * inv : 0.f;
    ushort4 hv, lv;
    split2(v[0], hv.x, lv.x); split2(v[1], hv.y, lv.y);
    split2(v[2], hv.z, lv.z); split2(v[3], hv.w, lv.w);
    int base = r * TP + q * 8 + h * 4;
    *(ushort4*)(hi + base) = hv;
    *(ushort4*)(lo + base) = lv;
  }
}

// Stage feat tile (phase E) with coherent vector loads.
__device__ __forceinline__ void stage_feat4(const float* __restrict__ feat, int k0,
                                            ushort* __restrict__ hi, ushort* __restrict__ lo, int t) {
  int r = t >> 2, q = t & 3;
#pragma unroll
  for (int h = 0; h < 2; ++h) {
    floatx4 v = cld4(feat + (size_t)r * 2048 + k0 + q * 8 + h * 4);
    ushort4 hv, lv;
    split2(v[0], hv.x, lv.x); split2(v[1], hv.y, lv.y);
    split2(v[2], hv.z, lv.z); split2(v[3], hv.w, lv.w);
    int base = r * TP + q * 8 + h * 4;
    *(ushort4*)(hi + base) = hv;
    *(ushort4*)(lo + base) = lv;
  }
}

// Stage 32 k-rows x 64 n-cols of row-major-N INPUT matrix B[k][n] into hi/lo LDS [n][k].
__device__ __forceinline__ void stage_tr_bf(const float* __restrict__ M, int ldN, int k0, int kmax,
                                            int n0, ushort* __restrict__ hi, ushort* __restrict__ lo, int t) {
  int kk = t >> 3, c8 = (t & 7) * 8;
  int gk = k0 + kk;
  const float* src = M + (size_t)gk * ldN + n0 + c8;
  float4 v0 = make_float4(0.f, 0.f, 0.f, 0.f), v1 = v0;
  if (gk < kmax) { v0 = *(const float4*)src; v1 = *(const float4*)(src + 4); }
#pragma unroll
  for (int j = 0; j < 8; ++j) {
    float f = (j < 4) ? ((float*)&v0)[j] : ((float*)&v1)[j - 4];
    ushort h, l;
    split2(f, h, l);
    hi[(c8 + j) * TP + kk] = h;
    lo[(c8 + j) * TP + kk] = l;
  }
}

#define MFMA(a, b, c) __builtin_amdgcn_mfma_f32_16x16x32_bf16(a, b, c, 0, 0, 0)

#define NBLK 512

// Two-phase broadcast barrier + explicit per-wave vmem drain.
__device__ __forceinline__ void gbar(unsigned* __restrict__ ctr, unsigned* __restrict__ flag,
                                     unsigned phase) {
  asm volatile("s_waitcnt vmcnt(0)" ::: "memory");
  __syncthreads();
  int t = threadIdx.x;
  if (t == 0)
    __hip_atomic_fetch_add(ctr + (blockIdx.x & 63) * 16, 1u, __ATOMIC_RELAXED, __HIP_MEMORY_SCOPE_AGENT);
  if (blockIdx.x == 0) {
    if (t < 64) {
      unsigned target = (unsigned)NBLK * phase;
      for (;;) {
        unsigned v = __hip_atomic_load(ctr + t * 16, __ATOMIC_RELAXED, __HIP_MEMORY_SCOPE_AGENT);
#pragma unroll
        for (int off = 32; off > 0; off >>= 1) v += __shfl_down(v, off, 64);
        v = __shfl(v, 0, 64);
        if (v >= target) break;
        __builtin_amdgcn_s_sleep(1);
      }
      if (t == 0)
        __hip_atomic_store(flag + phase * 16, 1u, __ATOMIC_RELAXED, __HIP_MEMORY_SCOPE_AGENT);
    }
  } else {
    if (t == 0) {
      while (__hip_atomic_load(flag + phase * 16, __ATOMIC_RELAXED, __HIP_MEMORY_SCOPE_AGENT) == 0u)
        __builtin_amdgcn_s_sleep(2);
    }
  }
  __syncthreads();
}

__global__ void k_init(unsigned* ctr) {
  int t = threadIdx.x;
#pragma unroll
  for (int i = 0; i < 5; ++i)
    __hip_atomic_store(ctr + i * 256 + t, 0u, __ATOMIC_RELAXED, __HIP_MEMORY_SCOPE_AGENT);
}

__global__ __launch_bounds__(256) void k_all(
    const float* __restrict__ x, const float* __restrict__ cent,
    const float* __restrict__ whall, const float* __restrict__ bhall,
    const float* __restrict__ wsel, const float* __restrict__ bsel,
    const float* __restrict__ wcos, float* __restrict__ ws, float* __restrict__ out) {
  __shared__ __align__(16) char smem[6 * 64 * TP * 2];   // 30720 B
  ushort* Ah  = (ushort*)smem;
  ushort* Al  = Ah + 64 * TP;
  ushort* B1h = Ah + 2 * 64 * TP;
  ushort* B1l = Ah + 3 * 64 * TP;
  ushort* B2h = Ah + 4 * 64 * TP;
  ushort* B2l = Ah + 5 * 64 * TP;
  float* red2 = (float*)smem;            // B1: [8][32][8] = 8 KB
  float* tf   = (float*)smem;            // GEMM epilogue: [64][65] f32 = 16.6 KB

  int bx = blockIdx.x, t = threadIdx.x;
  int lane = t & 63, w = t >> 6;
  int ln15 = t & 15, lq = (t >> 4) & 3, q8 = lq * 8;
  int mh = w & 1, nh = w >> 1;
  int erow = t >> 2, ec0 = (t & 3) * 16;   // epilogue row / col-chunk
  unsigned* ctr  = (unsigned*)(ws + OFF_CTR);
  unsigned* flag = (unsigned*)(ws + OFF_FLAG);

  // ---------------- Phase A: row norms + GEMM1 ----------------
  for (int r = bx * 4 + w; r < 2064; r += 2048) {
    const float* src = (r < 1000) ? cent + (size_t)r * FF
                     : (r < 2000) ? wcos + (size_t)(r - 1000) * FF
                                  : x + (size_t)(r - 2000) * FF;
    float s = 0.f;
#pragma unroll
    for (int i = 0; i < 8; ++i) {
      float4 v = *(const float4*)(src + i * 256 + lane * 4);
      s += v.x * v.x + v.y * v.y + v.z * v.z + v.w * v.w;
    }
#pragma unroll
    for (int off = 32; off > 0; off >>= 1) s += __shfl_down(s, off, 64);
    if (lane == 0) {
      if (r < 1000) cst(ws + OFF_CN2 + r, s);
      else if (r < 2000) cst(ws + OFF_WINV + (r - 1000), 1.f / sqrtf(s));
      else cst(ws + OFF_XN2 + (r - 2000), s);
    }
  }

  if (bx < 128) {
    // dual GEMM: S=x@cent^T, H=x@whall^T. 16 tiles x 8 splits, slab 256.
    int tile = bx & 15, ks = bx >> 4;
    int n0 = tile * 64;
    floatx4 accS[2][2], accH[2][2];
#pragma unroll
    for (int i = 0; i < 2; ++i)
#pragma unroll
      for (int j = 0; j < 2; ++j) { accS[i][j] = (floatx4){0.f,0.f,0.f,0.f}; accH[i][j] = (floatx4){0.f,0.f,0.f,0.f}; }
    for (int kc = 0; kc < 8; ++kc) {
      int k0 = ks * 256 + kc * 32;
      __syncthreads();
      stage_bt_bf(x,     FF, 0,  64,   k0, FF, Ah,  Al,  t);
      stage_bt_bf(cent,  FF, n0, 1000, k0, FF, B1h, B1l, t);
      stage_bt_bf(whall, FF, n0, 1000, k0, FF, B2h, B2l, t);
      __syncthreads();
      short8 ah[2], al[2];
#pragma unroll
      for (int i = 0; i < 2; ++i) {
        int row = (mh * 2 + i) * 16 + ln15;
        ah[i] = *(const short8*)(Ah + row * TP + q8);
        al[i] = *(const short8*)(Al + row * TP + q8);
      }
#pragma unroll
      for (int j = 0; j < 2; ++j) {
        int brow = (nh * 2 + j) * 16 + ln15;
        short8 b1h = *(const short8*)(B1h + brow * TP + q8);
        short8 b1l = *(const short8*)(B1l + brow * TP + q8);
        short8 b2h = *(const short8*)(B2h + brow * TP + q8);
        short8 b2l = *(const short8*)(B2l + brow * TP + q8);
#pragma unroll
        for (int i = 0; i < 2; ++i) {
          accS[i][j] = MFMA(ah[i], b1h, accS[i][j]);
          accS[i][j] = MFMA(ah[i], b1l, accS[i][j]);
          accS[i][j] = MFMA(al[i], b1h, accS[i][j]);
          accH[i][j] = MFMA(ah[i], b2h, accH[i][j]);
          accH[i][j] = MFMA(ah[i], b2l, accH[i][j]);
          accH[i][j] = MFMA(al[i], b2h, accH[i][j]);
        }
      }
    }
    // Epilogue via LDS transpose: fragment -> [64][65] tile -> row-major cst4.
    float* Spart = ws + OFF_SPART + (size_t)ks * 64000;
    float* Hpart = ws + OFF_HPART + (size_t)ks * 64000;
    __syncthreads();
#pragma unroll
    for (int i = 0; i < 2; ++i)
#pragma unroll
      for (int j = 0; j < 2; ++j) {
        int rr = (mh * 2 + i) * 16 + lq * 4;
        int cc = (nh * 2 + j) * 16 + ln15;
#pragma unroll
        for (int r = 0; r < 4; ++r) tf[(rr + r) * 65 + cc] = accS[i][j][r];
      }
    __syncthreads();
#pragma unroll
    for (int h = 0; h < 4; ++h) {
      int gn = n0 + ec0 + h * 4;
      if (gn < 1000) {
        floatx4 v = {tf[erow * 65 + ec0 + h * 4 + 0], tf[erow * 65 + ec0 + h * 4 + 1],
                     tf[erow * 65 + ec0 + h * 4 + 2], tf[erow * 65 + ec0 + h * 4 + 3]};
        cst4(Spart + erow * 1000 + gn, v);
      }
    }
    __syncthreads();
#pragma unroll
    for (int i = 0; i < 2; ++i)
#pragma unroll
      for (int j = 0; j < 2; ++j) {
        int rr = (mh * 2 + i) * 16 + lq * 4;
        int cc = (nh * 2 + j) * 16 + ln15;
#pragma unroll
        for (int r = 0; r < 4; ++r) tf[(rr + r) * 65 + cc] = accH[i][j][r];
      }
    __syncthreads();
#pragma unroll
    for (int h = 0; h < 4; ++h) {
      int gn = n0 + ec0 + h * 4;
      if (gn < 1000) {
        floatx4 v = {tf[erow * 65 + ec0 + h * 4 + 0], tf[erow * 65 + ec0 + h * 4 + 1],
                     tf[erow * 65 + ec0 + h * 4 + 2], tf[erow * 65 + ec0 + h * 4 + 3]};
        cst4(Hpart + erow * 1000 + gn, v);
      }
    }
  } else if (bx < 384) {
    // selpre = x@wsel^T. 32 tiles x 8 splits, slab 256.
    int b2 = bx - 128;
    int tile = b2 & 31, ks = b2 >> 5;
    int n0 = tile * 64;
    floatx4 acc[2][2];
#pragma unroll
    for (int i = 0; i < 2; ++i)
#pragma unroll
      for (int j = 0; j < 2; ++j) acc[i][j] = (floatx4){0.f,0.f,0.f,0.f};
    for (int kc = 0; kc < 8; ++kc) {
      int k0 = ks * 256 + kc * 32;
      __syncthreads();
      stage_bt_bf(x,    FF, 0,  64, k0, FF, Ah,  Al,  t);
      stage_bt_bf(wsel, FF, n0, FF, k0, FF, B1h, B1l, t);
      __syncthreads();
      short8 ah[2], al[2];
#pragma unroll
      for (int i = 0; i < 2; ++i) {
        int row = (mh * 2 + i) * 16 + ln15;
        ah[i] = *(const short8*)(Ah + row * TP + q8);
        al[i] = *(const short8*)(Al + row * TP + q8);
      }
#pragma unroll
      for (int j = 0; j < 2; ++j) {
        int brow = (nh * 2 + j) * 16 + ln15;
        short8 bh = *(const short8*)(B1h + brow * TP + q8);
        short8 bl = *(const short8*)(B1l + brow * TP + q8);
#pragma unroll
        for (int i = 0; i < 2; ++i) {
          acc[i][j] = MFMA(ah[i], bh, acc[i][j]);
          acc[i][j] = MFMA(ah[i], bl, acc[i][j]);
          acc[i][j] = MFMA(al[i], bh, acc[i][j]);
        }
      }
    }
    float* selp = ws + OFF_SELP + (size_t)ks * 131072;
    __syncthreads();
#pragma unroll
    for (int i = 0; i < 2; ++i)
#pragma unroll
      for (int j = 0; j < 2; ++j) {
        int rr = (mh * 2 + i) * 16 + lq * 4;
        int cc = (nh * 2 + j) * 16 + ln15;
#pragma unroll
        for (int r = 0; r < 4; ++r) tf[(rr + r) * 65 + cc] = acc[i][j][r];
      }
    __syncthreads();
#pragma unroll
    for (int h = 0; h < 4; ++h) {
      floatx4 v = {tf[erow * 65 + ec0 + h * 4 + 0], tf[erow * 65 + ec0 + h * 4 + 1],
                   tf[erow * 65 + ec0 + h * 4 + 2], tf[erow * 65 + ec0 + h * 4 + 3]};
      cst4(selp + erow * 2048 + n0 + ec0 + h * 4, v);
    }
  }

  gbar(ctr, flag, 1);

  // ---------------- Phase B1: partial reduce (depth 8) + chunk softmax stats ----------------
  {
    int b = bx >> 3, ch = bx & 7;
    int g = t >> 5, ci = t & 31;
    int c = ch * 128 + ci * 4;
    const float* Sp = ws + OFF_SPART + (size_t)g * 64000 + b * 1000 + c;
    const float* Hp = ws + OFF_HPART + (size_t)g * 64000 + b * 1000 + c;
    floatx4 s1, h1;
    cld4x2(Sp, Hp, s1, h1);
#pragma unroll
    for (int j = 0; j < 4; ++j) {
      red2[(g * 32 + ci) * 8 + j]     = s1[j];
      red2[(g * 32 + ci) * 8 + 4 + j] = h1[j];
    }
    __syncthreads();
    if (t < 32) {
      float S[4] = {0,0,0,0}, H[4] = {0,0,0,0};
#pragma unroll
      for (int g2 = 0; g2 < 8; ++g2)
#pragma unroll
        for (int j = 0; j < 4; ++j) {
          S[j] += red2[(g2 * 32 + t) * 8 + j];
          H[j] += red2[(g2 * 32 + t) * 8 + 4 + j];
        }
      int c0 = ch * 128 + t * 4;
      float xn = cld(ws + OFF_XN2 + b);
      float Hf[4], lmin = 3.0e38f, lmax = -3.0e38f;
#pragma unroll
      for (int j = 0; j < 4; ++j) {
        bool valid = (c0 + j) < 1000;
        float bh = valid ? bhall[c0 + j] : 0.f;
        Hf[j] = valid ? (H[j] + bh) : -3.0e38f;
        float cn = valid ? cld(ws + OFF_CN2 + c0 + j) : 0.f;
        float d2 = valid ? (xn - 2.f * S[j] + cn) : 3.0e38f;
        lmin = fminf(lmin, d2);
        lmax = fmaxf(lmax, Hf[j]);
      }
      cst4(ws + OFF_HROW + b * 1024 + c0, (floatx4){Hf[0], Hf[1], Hf[2], Hf[3]});
      float cmin = lmin, cmax = lmax;
#pragma unroll
      for (int off = 16; off > 0; off >>= 1) {
        cmin = fminf(cmin, __shfl_down(cmin, off, 32));
        cmax = fmaxf(cmax, __shfl_down(cmax, off, 32));
      }
      cmin = __shfl(cmin, 0, 32);
      cmax = __shfl(cmax, 0, 32);
      float lsum = 0.f;
#pragma unroll
      for (int j = 0; j < 4; ++j)
        if ((c0 + j) < 1000) lsum += expf(Hf[j] - cmax);
#pragma unroll
      for (int off = 16; off > 0; off >>= 1) lsum += __shfl_down(lsum, off, 32);
      if (t == 0) {
        float* mm = ws + OFF_MM + (b * 8 + ch) * 4;
        cst(mm + 0, cmin);
        cst(mm + 1, cmax);
        cst(mm + 2, lsum);
      }
    }
  }

  gbar(ctr, flag, 2);

  // ---------------- Phase B2: per-row finalize ----------------
  if (bx < 64 && t < 8) {
    const float* mm = ws + OFF_MM + (bx * 8 + t) * 4;
    float mn = cld(mm + 0), mx = cld(mm + 1), sm = cld(mm + 2);
    float gmin = mn, gmax = mx;
#pragma unroll
    for (int off = 4; off > 0; off >>= 1) {
      gmin = fminf(gmin, __shfl_down(gmin, off, 8));
      gmax = fmaxf(gmax, __shfl_down(gmax, off, 8));
    }
    gmin = __shfl(gmin, 0, 8);
    gmax = __shfl(gmax, 0, 8);
    float dp = sm * expf(mx - gmax);
#pragma unroll
    for (int off = 4; off > 0; off >>= 1) dp += __shfl_down(dp, off, 8);
    if (t == 0) {
      float* rf = ws + OFF_ROWF + bx * 4;
      cst(rf + 0, gmax);
      cst(rf + 1, 1.f / dp);
      cst(rf + 2, 10.f / sqrtf(gmin));
    }
  }

  gbar(ctr, flag, 3);

  // ---------------- Phase C: mem = V@cent (K=1000,N=2048). 32 tiles x 8 splits, slab 128 ----------------
  if (bx < 256) {
    int tile = bx & 31, ks = bx >> 5;
    int n0 = tile * 64;
    int vr = t >> 2;
    float gm  = cld(ws + OFF_ROWF + vr * 4 + 0);
    float inv = cld(ws + OFF_ROWF + vr * 4 + 1);
    floatx4 acc[2][2];
#pragma unroll
    for (int i = 0; i < 2; ++i)
#pragma unroll
      for (int j = 0; j < 2; ++j) acc[i][j] = (floatx4){0.f,0.f,0.f,0.f};
    for (int kc = 0; kc < 4; ++kc) {
      int k0 = ks * 128 + kc * 32;
      __syncthreads();
      stage_v(ws + OFF_HROW, gm, inv, k0, Ah, Al, t);
      stage_tr_bf(cent, FF, k0, 1000, n0, B1h, B1l, t);
      __syncthreads();
      short8 ah[2], al[2];
#pragma unroll
      for (int i = 0; i < 2; ++i) {
        int row = (mh * 2 + i) * 16 + ln15;
        ah[i] = *(const short8*)(Ah + row * TP + q8);
        al[i] = *(const short8*)(Al + row * TP + q8);
      }
#pragma unroll
      for (int j = 0; j < 2; ++j) {
        int brow = (nh * 2 + j) * 16 + ln15;
        short8 bh = *(const short8*)(B1h + brow * TP + q8);
        short8 bl = *(const short8*)(B1l + brow * TP + q8);
#pragma unroll
        for (int i = 0; i < 2; ++i) {
          acc[i][j] = MFMA(ah[i], bh, acc[i][j]);
          acc[i][j] = MFMA(ah[i], bl, acc[i][j]);
          acc[i][j] = MFMA(al[i], bh, acc[i][j]);
        }
      }
    }
    float* memp = ws + OFF_MEMP + (size_t)ks * 131072;
    __syncthreads();
#pragma unroll
    for (int i = 0; i < 2; ++i)
#pragma unroll
      for (int j = 0; j < 2; ++j) {
        int rr = (mh * 2 + i) * 16 + lq * 4;
        int cc = (nh * 2 + j) * 16 + ln15;
#pragma unroll
        for (int r = 0; r < 4; ++r) tf[(rr + r) * 65 + cc] = acc[i][j][r];
      }
    __syncthreads();
#pragma unroll
    for (int h = 0; h < 4; ++h) {
      floatx4 v = {tf[erow * 65 + ec0 + h * 4 + 0], tf[erow * 65 + ec0 + h * 4 + 1],
                   tf[erow * 65 + ec0 + h * 4 + 2], tf[erow * 65 + ec0 + h * 4 + 3]};
      cst4(memp + erow * 2048 + n0 + ec0 + h * 4, v);
    }
  }

  gbar(ctr, flag, 4);

  // ---------------- Phase D: fuse, float4-wide. 64 rows x 8 chunks of 256 feats ----------------
  if (t < 64) {
    int row = bx >> 3, ch2 = bx & 7;
    int f = ch2 * 256 + t * 4;
    const float* selp = ws + OFF_SELP + (size_t)row * 2048 + f;
    const float* memp = ws + OFF_MEMP + (size_t)row * 2048 + f;
    floatx4 a0, a1, a2, a3;
    float sp[4], mm4[4];
#pragma unroll
    for (int j = 0; j < 4; ++j) { sp[j] = 0.f; mm4[j] = 0.f; }
#pragma unroll
    for (int q = 0; q < 2; ++q) {
      cld4x4(selp + (size_t)(4 * q) * 131072, selp + (size_t)(4 * q + 1) * 131072,
             selp + (size_t)(4 * q + 2) * 131072, selp + (size_t)(4 * q + 3) * 131072,
             a0, a1, a2, a3);
#pragma unroll
      for (int j = 0; j < 4; ++j)
        sp[j] += a0[j] + a1[j] + a2[j] + a3[j];
    }
#pragma unroll
    for (int q = 0; q < 2; ++q) {
      cld4x4(memp + (size_t)(4 * q) * 131072, memp + (size_t)(4 * q + 1) * 131072,
             memp + (size_t)(4 * q + 2) * 131072, memp + (size_t)(4 * q + 3) * 131072,
             a0, a1, a2, a3);
#pragma unroll
      for (int j = 0; j < 4; ++j)
        mm4[j] += a0[j] + a1[j] + a2[j] + a3[j];
    }
    float4 bs4 = *(const float4*)(bsel + f);
    float4 x4  = *(const float4*)(x + (size_t)row * 2048 + f);
    float rch = cld(ws + OFF_ROWF + row * 4 + 2);
    float4 inf4;
    floatx4 ft4;
    float nrm2 = 0.f;
#pragma unroll
    for (int j = 0; j < 4; ++j) {
      float sel = tanhf(sp[j] + ((float*)&bs4)[j]);
      float inf = sel * mm4[j];
      float ft = rch * (((float*)&x4)[j] + inf);
      ((float*)&inf4)[j] = inf;
      ft4[j] = ft;
      nrm2 += ft * ft;
    }
    *(float4*)(out + 64000 + (size_t)row * 2048 + f) = x4;     // direct_feature
    *(float4*)(out + 195072 + (size_t)row * 2048 + f) = inf4;  // infused_feature
    cst4(ws + OFF_FEAT + (size_t)row * 2048 + f, ft4);
#pragma unroll
    for (int off = 32; off > 0; off >>= 1) nrm2 += __shfl_down(nrm2, off, 64);
    if (t == 0) cst(ws + OFF_NRM2P + row * 8 + ch2, nrm2);
  }

  gbar(ctr, flag, 5);

  // ---------------- Phase E: logp = feat@wcos^T (K=2048,N=1000). 16 tiles x 16 splits, slab 128 ----------------
  if (bx < 256) {
    int tile = bx & 15, ks = bx >> 4;
    int n0 = tile * 64;
    floatx4 acc[2][2];
#pragma unroll
    for (int i = 0; i < 2; ++i)
#pragma unroll
      for (int j = 0; j < 2; ++j) acc[i][j] = (floatx4){0.f,0.f,0.f,0.f};
    for (int kc = 0; kc < 4; ++kc) {
      int k0 = ks * 128 + kc * 32;
      __syncthreads();
      stage_feat4(ws + OFF_FEAT, k0, Ah, Al, t);
      stage_bt_bf(wcos, FF, n0, 1000, k0, FF, B1h, B1l, t);
      __syncthreads();
      short8 ah[2], al[2];
#pragma unroll
      for (int i = 0; i < 2; ++i) {
        int row = (mh * 2 + i) * 16 + ln15;
        ah[i] = *(const short8*)(Ah + row * TP + q8);
        al[i] = *(const short8*)(Al + row * TP + q8);
      }
#pragma unroll
      for (int j = 0; j < 2; ++j) {
        int brow = (nh * 2 + j) * 16 + ln15;
        short8 bh = *(const short8*)(B1h + brow * TP + q8);
        short8 bl = *(const short8*)(B1l + brow * TP + q8);
#pragma unroll
        for (int i = 0; i < 2; ++i) {
          acc[i][j] = MFMA(ah[i], bh, acc[i][j]);
          acc[i][j] = MFMA(ah[i], bl, acc[i][j]);
          acc[i][j] = MFMA(al[i], bh, acc[i][j]);
        }
      }
    }
    float* logp = ws + OFF_LOGP + (size_t)ks * 64000;
    __syncthreads();
#pragma unroll
    for (int i = 0; i < 2; ++i)
#pragma unroll
      for (int j = 0; j < 2; ++j) {
        int rr = (mh * 2 + i) * 16 + lq * 4;
        int cc = (nh * 2 + j) * 16 + ln15;
#pragma unroll
        for (int r = 0; r < 4; ++r) tf[(rr + r) * 65 + cc] = acc[i][j][r];
      }
    __syncthreads();
#pragma unroll
    for (int h = 0; h < 4; ++h) {
      int gn = n0 + ec0 + h * 4;
      if (gn < 1000) {
        floatx4 v = {tf[erow * 65 + ec0 + h * 4 + 0], tf[erow * 65 + ec0 + h * 4 + 1],
                     tf[erow * 65 + ec0 + h * 4 + 2], tf[erow * 65 + ec0 + h * 4 + 3]};
        cst4(logp + erow * 1000 + gn, v);
      }
    }
  }

  gbar(ctr, flag, 6);

  // ---------------- Phase F: reduce 16 logit partials, float4-wide ----------------
  if (bx < 500 && t < 32) {
    int idx0 = (bx * 32 + t) * 4;
    const float* logp = ws + OFF_LOGP + idx0;
    float s4[4] = {0,0,0,0};
    floatx4 a0, a1, a2, a3;
#pragma unroll
    for (int q = 0; q < 4; ++q) {
      cld4x4(logp + (size_t)(4 * q) * 64000, logp + (size_t)(4 * q + 1) * 64000,
             logp + (size_t)(4 * q + 2) * 64000, logp + (size_t)(4 * q + 3) * 64000,
             a0, a1, a2, a3);
#pragma unroll
      for (int j = 0; j < 4; ++j)
        s4[j] += a0[j] + a1[j] + a2[j] + a3[j];
    }
    floatx4 o4;
    int pb = -1;
    float sfac = 0.f;
#pragma unroll
    for (int j = 0; j < 4; ++j) {
      int idx = idx0 + j;
      int bb = idx / 1000;
      int cc = idx - bb * 1000;
      if (bb != pb) {
        float n2 = 0.f;
#pragma unroll
        for (int q = 0; q < 8; ++q) n2 += cld(ws + OFF_NRM2P + bb * 8 + q);
        sfac = 16.f / (1.f + sqrtf(n2));
        pb = bb;
      }
      o4[j] = s4[j] * sfac * cld(ws + OFF_WINV + cc);
    }
    *(floatx4*)(out + idx0) = o4;
  }
}

extern "C" void kernel_launch(void* const* d_in, const int* in_sizes, int n_in,
                              void* d_out, int out_size, void* d_ws, size_t ws_size,
                              hipStream_t stream) {
  const float* x     = (const float*)d_in[0];
  const float* cent  = (const float*)d_in[1];
  const float* whall = (const float*)d_in[2];
  const float* bhall = (const float*)d_in[3];
  const float* wsel  = (const float*)d_in[4];
  const float* bsel  = (const float*)d_in[5];
  const float* wcos  = (const float*)d_in[6];
  float* out = (float*)d_out;
  float* ws  = (float*)d_ws;
  unsigned* ctr = (unsigned*)(ws + OFF_CTR);

  hipLaunchKernelGGL(k_init, dim3(1), dim3(256), 0, stream, ctr);
  hipLaunchKernelGGL(k_all, dim3(NBLK), dim3(256), 0, stream,
                     x, cent, whall, bhall, wsel, bsel, wcos, ws, out);
}

// Round 14
// 133.135 us; speedup vs baseline: 1.1040x; 1.1040x over previous
//
#include <hip/hip_runtime.h>
#include <math.h>

#define FF 2048

typedef __attribute__((ext_vector_type(8))) short short8;
typedef __attribute__((ext_vector_type(4))) float floatx4;

// ws float offsets (split-K: 8/8/8/16). All traffic NORMAL cached ops now —
// kernel boundaries provide cross-block coherence (no sc0/sc1 anywhere).
#define OFF_SPART 0                      // [8][64][1000]
#define OFF_HPART 512000                 // [8][64][1000]
#define OFF_SELP  1024000                // [8][64][2048]
#define OFF_MEMP  2072576                // [8][64][2048]
#define OFF_LOGP  3121152                // [16][64][1000]
#define OFF_V     4145152                // [64][1024] softmax result (padded)
#define OFF_FEAT  4210688                // [64][2048]
#define OFF_CN2   4341760                // [1000]
#define OFF_WINV  4342760                // [1000]
#define OFF_XN2   4343760                // [64]
#define OFF_REACH 4343824                // [64]
#define OFF_NRM2P 4343888                // [64][8]

#define TP 40   // LDS tile pitch in shorts: 32 data + 8 pad

__device__ __forceinline__ void split2(float f, ushort& h, ushort& l) {
  unsigned u = __float_as_uint(f);
  float r = f - __uint_as_float(u & 0xffff0000u);
  h = (ushort)(u >> 16);
  l = (ushort)(__float_as_uint(r) >> 16);
}

// Stage 64 rows x 32 k of row-major-K matrix into hi/lo bf16 LDS [64][TP].
__device__ __forceinline__ void stage_bt_bf(const float* __restrict__ M, int ldK, int rowBase,
                                            int nrows, int k0, int kmax,
                                            ushort* __restrict__ hi, ushort* __restrict__ lo, int t) {
  int r = t >> 2, q = t & 3;
  int grow = rowBase + r;
  bool rok = grow < nrows;
  const float* src = M + (size_t)grow * ldK + k0 + q * 8;
#pragma unroll
  for (int h = 0; h < 2; ++h) {
    int kb = k0 + q * 8 + h * 4;
    float4 v = make_float4(0.f, 0.f, 0.f, 0.f);
    if (rok) {
      if (kb + 3 < kmax) {
        v = *(const float4*)(src + h * 4);
      } else {
#pragma unroll
        for (int j = 0; j < 4; ++j)
          if (kb + j < kmax) ((float*)&v)[j] = src[h * 4 + j];
      }
    }
    ushort4 hv, lv;
    split2(v.x, hv.x, lv.x); split2(v.y, hv.y, lv.y);
    split2(v.z, hv.z, lv.z); split2(v.w, hv.w, lv.w);
    int base = r * TP + q * 8 + h * 4;
    *(ushort4*)(hi + base) = hv;
    *(ushort4*)(lo + base) = lv;
  }
}

// Stage 32 k-rows x 64 n-cols of row-major-N matrix B[k][n] into hi/lo LDS [n][k].
__device__ __forceinline__ void stage_tr_bf(const float* __restrict__ M, int ldN, int k0, int kmax,
                                            int n0, ushort* __restrict__ hi, ushort* __restrict__ lo, int t) {
  int kk = t >> 3, c8 = (t & 7) * 8;
  int gk = k0 + kk;
  const float* src = M + (size_t)gk * ldN + n0 + c8;
  float4 v0 = make_float4(0.f, 0.f, 0.f, 0.f), v1 = v0;
  if (gk < kmax) { v0 = *(const float4*)src; v1 = *(const float4*)(src + 4); }
#pragma unroll
  for (int j = 0; j < 8; ++j) {
    float f = (j < 4) ? ((float*)&v0)[j] : ((float*)&v1)[j - 4];
    ushort h, l;
    split2(f, h, l);
    hi[(c8 + j) * TP + kk] = h;
    lo[(c8 + j) * TP + kk] = l;
  }
}

#define MFMA(a, b, c) __builtin_amdgcn_mfma_f32_16x16x32_bf16(a, b, c, 0, 0, 0)

// ================= Kernel A: row norms + GEMM1 (S,H dual / selpre) =================
__global__ __launch_bounds__(256) void ka_gemm1(
    const float* __restrict__ x, const float* __restrict__ cent,
    const float* __restrict__ whall, const float* __restrict__ wsel,
    const float* __restrict__ wcos, float* __restrict__ ws) {
  __shared__ __align__(16) ushort u_lds[6 * 64 * TP];
  ushort* Ah  = u_lds;
  ushort* Al  = u_lds + 64 * TP;
  ushort* B1h = u_lds + 2 * 64 * TP;
  ushort* B1l = u_lds + 3 * 64 * TP;
  ushort* B2h = u_lds + 4 * 64 * TP;
  ushort* B2l = u_lds + 5 * 64 * TP;
  int bx = blockIdx.x, t = threadIdx.x;
  int lane = t & 63, w = t >> 6;
  int ln15 = t & 15, lq = (t >> 4) & 3, q8 = lq * 8;
  int mh = w & 1, nh = w >> 1;

  for (int r = bx * 4 + w; r < 2064; r += 2048) {
    const float* src = (r < 1000) ? cent + (size_t)r * FF
                     : (r < 2000) ? wcos + (size_t)(r - 1000) * FF
                                  : x + (size_t)(r - 2000) * FF;
    float s = 0.f;
#pragma unroll
    for (int i = 0; i < 8; ++i) {
      float4 v = *(const float4*)(src + i * 256 + lane * 4);
      s += v.x * v.x + v.y * v.y + v.z * v.z + v.w * v.w;
    }
#pragma unroll
    for (int off = 32; off > 0; off >>= 1) s += __shfl_down(s, off, 64);
    if (lane == 0) {
      if (r < 1000) ws[OFF_CN2 + r] = s;
      else if (r < 2000) ws[OFF_WINV + (r - 1000)] = 1.f / sqrtf(s);
      else ws[OFF_XN2 + (r - 2000)] = s;
    }
  }

  if (bx < 128) {
    int tile = bx & 15, ks = bx >> 4;
    int n0 = tile * 64;
    floatx4 accS[2][2], accH[2][2];
#pragma unroll
    for (int i = 0; i < 2; ++i)
#pragma unroll
      for (int j = 0; j < 2; ++j) { accS[i][j] = (floatx4){0.f,0.f,0.f,0.f}; accH[i][j] = (floatx4){0.f,0.f,0.f,0.f}; }
    for (int kc = 0; kc < 8; ++kc) {
      int k0 = ks * 256 + kc * 32;
      __syncthreads();
      stage_bt_bf(x,     FF, 0,  64,   k0, FF, Ah,  Al,  t);
      stage_bt_bf(cent,  FF, n0, 1000, k0, FF, B1h, B1l, t);
      stage_bt_bf(whall, FF, n0, 1000, k0, FF, B2h, B2l, t);
      __syncthreads();
      short8 ah[2], al[2];
#pragma unroll
      for (int i = 0; i < 2; ++i) {
        int row = (mh * 2 + i) * 16 + ln15;
        ah[i] = *(const short8*)(Ah + row * TP + q8);
        al[i] = *(const short8*)(Al + row * TP + q8);
      }
#pragma unroll
      for (int j = 0; j < 2; ++j) {
        int brow = (nh * 2 + j) * 16 + ln15;
        short8 b1h = *(const short8*)(B1h + brow * TP + q8);
        short8 b1l = *(const short8*)(B1l + brow * TP + q8);
        short8 b2h = *(const short8*)(B2h + brow * TP + q8);
        short8 b2l = *(const short8*)(B2l + brow * TP + q8);
#pragma unroll
        for (int i = 0; i < 2; ++i) {
          accS[i][j] = MFMA(ah[i], b1h, accS[i][j]);
          accS[i][j] = MFMA(ah[i], b1l, accS[i][j]);
          accS[i][j] = MFMA(al[i], b1h, accS[i][j]);
          accH[i][j] = MFMA(ah[i], b2h, accH[i][j]);
          accH[i][j] = MFMA(ah[i], b2l, accH[i][j]);
          accH[i][j] = MFMA(al[i], b2h, accH[i][j]);
        }
      }
    }
    float* Spart = ws + OFF_SPART + (size_t)ks * 64000;
    float* Hpart = ws + OFF_HPART + (size_t)ks * 64000;
#pragma unroll
    for (int i = 0; i < 2; ++i)
#pragma unroll
      for (int j = 0; j < 2; ++j) {
        int gn = n0 + (nh * 2 + j) * 16 + ln15;
        if (gn < 1000) {
#pragma unroll
          for (int r = 0; r < 4; ++r) {
            int gm = (mh * 2 + i) * 16 + lq * 4 + r;
            Spart[gm * 1000 + gn] = accS[i][j][r];
            Hpart[gm * 1000 + gn] = accH[i][j][r];
          }
        }
      }
  } else if (bx < 384) {
    int b2 = bx - 128;
    int tile = b2 & 31, ks = b2 >> 5;
    int n0 = tile * 64;
    floatx4 acc[2][2];
#pragma unroll
    for (int i = 0; i < 2; ++i)
#pragma unroll
      for (int j = 0; j < 2; ++j) acc[i][j] = (floatx4){0.f,0.f,0.f,0.f};
    for (int kc = 0; kc < 8; ++kc) {
      int k0 = ks * 256 + kc * 32;
      __syncthreads();
      stage_bt_bf(x,    FF, 0,  64, k0, FF, Ah,  Al,  t);
      stage_bt_bf(wsel, FF, n0, FF, k0, FF, B1h, B1l, t);
      __syncthreads();
      short8 ah[2], al[2];
#pragma unroll
      for (int i = 0; i < 2; ++i) {
        int row = (mh * 2 + i) * 16 + ln15;
        ah[i] = *(const short8*)(Ah + row * TP + q8);
        al[i] = *(const short8*)(Al + row * TP + q8);
      }
#pragma unroll
      for (int j = 0; j < 2; ++j) {
        int brow = (nh * 2 + j) * 16 + ln15;
        short8 bh = *(const short8*)(B1h + brow * TP + q8);
        short8 bl = *(const short8*)(B1l + brow * TP + q8);
#pragma unroll
        for (int i = 0; i < 2; ++i) {
          acc[i][j] = MFMA(ah[i], bh, acc[i][j]);
          acc[i][j] = MFMA(ah[i], bl, acc[i][j]);
          acc[i][j] = MFMA(al[i], bh, acc[i][j]);
        }
      }
    }
    float* selp = ws + OFF_SELP + (size_t)ks * 131072;
#pragma unroll
    for (int i = 0; i < 2; ++i)
#pragma unroll
      for (int j = 0; j < 2; ++j) {
        int gn = n0 + (nh * 2 + j) * 16 + ln15;
#pragma unroll
        for (int r = 0; r < 4; ++r) {
          int gm = (mh * 2 + i) * 16 + lq * 4 + r;
          selp[gm * 2048 + gn] = acc[i][j][r];
        }
      }
  }
}

// ================= Kernel B: reduce partials, min-dist + softmax -> V, reach =================
__global__ __launch_bounds__(256) void kb_softmax(const float* __restrict__ bhall,
                                                  float* __restrict__ ws) {
  __shared__ float hrow[1000];
  __shared__ float red[256];
  int b = blockIdx.x, t = threadIdx.x;
  float xn = ws[OFF_XN2 + b];
  float lmin = 3.0e38f, lmax = -3.0e38f;
  if (t < 250) {
    int c0 = t * 4;
    floatx4 S = {0.f,0.f,0.f,0.f}, H = {0.f,0.f,0.f,0.f};
#pragma unroll
    for (int ks = 0; ks < 8; ++ks) {
      floatx4 sv = *(const floatx4*)(ws + OFF_SPART + (size_t)ks * 64000 + b * 1000 + c0);
      floatx4 hv = *(const floatx4*)(ws + OFF_HPART + (size_t)ks * 64000 + b * 1000 + c0);
      S += sv; H += hv;
    }
    floatx4 bh = *(const floatx4*)(bhall + c0);
    floatx4 cn = *(const floatx4*)(ws + OFF_CN2 + c0);
#pragma unroll
    for (int j = 0; j < 4; ++j) {
      float Hf = H[j] + bh[j];
      hrow[c0 + j] = Hf;
      float d2 = xn - 2.f * S[j] + cn[j];
      lmin = fminf(lmin, d2);
      lmax = fmaxf(lmax, Hf);
    }
  }
  red[t] = lmin; __syncthreads();
  for (int s = 128; s > 0; s >>= 1) { if (t < s) red[t] = fminf(red[t], red[t + s]); __syncthreads(); }
  float bmin = red[0]; __syncthreads();
  red[t] = lmax; __syncthreads();
  for (int s = 128; s > 0; s >>= 1) { if (t < s) red[t] = fmaxf(red[t], red[t + s]); __syncthreads(); }
  float bmax = red[0]; __syncthreads();
  float lsum = 0.f;
  float e4[4] = {0.f, 0.f, 0.f, 0.f};
  if (t < 250) {
#pragma unroll
    for (int j = 0; j < 4; ++j) {
      e4[j] = expf(hrow[t * 4 + j] - bmax);
      lsum += e4[j];
    }
  }
  red[t] = lsum; __syncthreads();
  for (int s = 128; s > 0; s >>= 1) { if (t < s) red[t] += red[t + s]; __syncthreads(); }
  float inv = 1.f / red[0];
  if (t < 250)
    *(floatx4*)(ws + OFF_V + b * 1024 + t * 4) =
        (floatx4){e4[0] * inv, e4[1] * inv, e4[2] * inv, e4[3] * inv};
  if (t == 250) {  // pad V[1000..1023] with zeros so phase C can load blindly
#pragma unroll
    for (int j = 0; j < 24; ++j) ws[OFF_V + b * 1024 + 1000 + j] = 0.f;
  }
  if (t == 0) ws[OFF_REACH + b] = 10.f / sqrtf(bmin);
}

// ================= Kernel C: mem = V@cent (K=1000,N=2048). 32 tiles x 8 splits =================
__global__ __launch_bounds__(256) void kc_mem(const float* __restrict__ cent,
                                              float* __restrict__ ws) {
  __shared__ __align__(16) ushort u_lds[4 * 64 * TP];
  ushort* Ah  = u_lds;
  ushort* Al  = u_lds + 64 * TP;
  ushort* B1h = u_lds + 2 * 64 * TP;
  ushort* B1l = u_lds + 3 * 64 * TP;
  int bx = blockIdx.x, t = threadIdx.x;
  int tile = bx & 31, ks = bx >> 5;
  int n0 = tile * 64;
  int ln15 = t & 15, lq = (t >> 4) & 3, q8 = lq * 8;
  int w = t >> 6, mh = w & 1, nh = w >> 1;
  const float* V = ws + OFF_V;
  floatx4 acc[2][2];
#pragma unroll
  for (int i = 0; i < 2; ++i)
#pragma unroll
    for (int j = 0; j < 2; ++j) acc[i][j] = (floatx4){0.f,0.f,0.f,0.f};
  for (int kc = 0; kc < 4; ++kc) {
    int k0 = ks * 128 + kc * 32;
    __syncthreads();
    // stage V rows (ld 1024, always valid due to padding)
    {
      int r = t >> 2, q = t & 3;
#pragma unroll
      for (int h = 0; h < 2; ++h) {
        float4 v = *(const float4*)(V + (size_t)r * 1024 + k0 + q * 8 + h * 4);
        ushort4 hv, lv;
        split2(v.x, hv.x, lv.x); split2(v.y, hv.y, lv.y);
        split2(v.z, hv.z, lv.z); split2(v.w, hv.w, lv.w);
        int base = r * TP + q * 8 + h * 4;
        *(ushort4*)(Ah + base) = hv;
        *(ushort4*)(Al + base) = lv;
      }
    }
    stage_tr_bf(cent, FF, k0, 1000, n0, B1h, B1l, t);
    __syncthreads();
    short8 ah[2], al[2];
#pragma unroll
    for (int i = 0; i < 2; ++i) {
      int row = (mh * 2 + i) * 16 + ln15;
      ah[i] = *(const short8*)(Ah + row * TP + q8);
      al[i] = *(const short8*)(Al + row * TP + q8);
    }
#pragma unroll
    for (int j = 0; j < 2; ++j) {
      int brow = (nh * 2 + j) * 16 + ln15;
      short8 bh = *(const short8*)(B1h + brow * TP + q8);
      short8 bl = *(const short8*)(B1l + brow * TP + q8);
#pragma unroll
      for (int i = 0; i < 2; ++i) {
        acc[i][j] = MFMA(ah[i], bh, acc[i][j]);
        acc[i][j] = MFMA(ah[i], bl, acc[i][j]);
        acc[i][j] = MFMA(al[i], bh, acc[i][j]);
      }
    }
  }
  float* memp = ws + OFF_MEMP + (size_t)ks * 131072;
#pragma unroll
  for (int i = 0; i < 2; ++i)
#pragma unroll
    for (int j = 0; j < 2; ++j) {
      int gn = n0 + (nh * 2 + j) * 16 + ln15;
#pragma unroll
      for (int r = 0; r < 4; ++r) {
        int gm = (mh * 2 + i) * 16 + lq * 4 + r;
        memp[gm * 2048 + gn] = acc[i][j][r];
      }
    }
}

// ================= Kernel D: fuse. 64 rows x 8 chunks, one wave each =================
__global__ __launch_bounds__(64) void kd_fuse(const float* __restrict__ x,
                                              const float* __restrict__ bsel,
                                              float* __restrict__ ws, float* __restrict__ out) {
  int bx = blockIdx.x, t = threadIdx.x;
  int row = bx >> 3, ch = bx & 7;
  int f = ch * 256 + t * 4;
  const float* selp = ws + OFF_SELP + (size_t)row * 2048 + f;
  const float* memp = ws + OFF_MEMP + (size_t)row * 2048 + f;
  floatx4 sp = {0.f,0.f,0.f,0.f}, mm = {0.f,0.f,0.f,0.f};
#pragma unroll
  for (int ks = 0; ks < 8; ++ks) {
    sp += *(const floatx4*)(selp + (size_t)ks * 131072);
    mm += *(const floatx4*)(memp + (size_t)ks * 131072);
  }
  float4 bs4 = *(const float4*)(bsel + f);
  float4 x4  = *(const float4*)(x + (size_t)row * 2048 + f);
  float rch = ws[OFF_REACH + row];
  float4 inf4;
  floatx4 ft4;
  float nrm2 = 0.f;
#pragma unroll
  for (int j = 0; j < 4; ++j) {
    float sel = tanhf(sp[j] + ((float*)&bs4)[j]);
    float inf = sel * mm[j];
    float ft = rch * (((float*)&x4)[j] + inf);
    ((float*)&inf4)[j] = inf;
    ft4[j] = ft;
    nrm2 += ft * ft;
  }
  *(float4*)(out + 64000 + (size_t)row * 2048 + f) = x4;     // direct_feature
  *(float4*)(out + 195072 + (size_t)row * 2048 + f) = inf4;  // infused_feature
  *(floatx4*)(ws + OFF_FEAT + (size_t)row * 2048 + f) = ft4;
#pragma unroll
  for (int off = 32; off > 0; off >>= 1) nrm2 += __shfl_down(nrm2, off, 64);
  if (t == 0) ws[OFF_NRM2P + row * 8 + ch] = nrm2;
}

// ================= Kernel E: logp = feat@wcos^T (K=2048,N=1000). 16 tiles x 16 splits =================
__global__ __launch_bounds__(256) void ke_logits(const float* __restrict__ wcos,
                                                 float* __restrict__ ws) {
  __shared__ __align__(16) ushort u_lds[4 * 64 * TP];
  ushort* Ah  = u_lds;
  ushort* Al  = u_lds + 64 * TP;
  ushort* B1h = u_lds + 2 * 64 * TP;
  ushort* B1l = u_lds + 3 * 64 * TP;
  int bx = blockIdx.x, t = threadIdx.x;
  int tile = bx & 15, ks = bx >> 4;
  int n0 = tile * 64;
  int ln15 = t & 15, lq = (t >> 4) & 3, q8 = lq * 8;
  int w = t >> 6, mh = w & 1, nh = w >> 1;
  const float* feat = ws + OFF_FEAT;
  floatx4 acc[2][2];
#pragma unroll
  for (int i = 0; i < 2; ++i)
#pragma unroll
    for (int j = 0; j < 2; ++j) acc[i][j] = (floatx4){0.f,0.f,0.f,0.f};
  for (int kc = 0; kc < 4; ++kc) {
    int k0 = ks * 128 + kc * 32;
    __syncthreads();
    {
      int r = t >> 2, q = t & 3;
#pragma unroll
      for (int h = 0; h < 2; ++h) {
        float4 v = *(const float4*)(feat + (size_t)r * 2048 + k0 + q * 8 + h * 4);
        ushort4 hv, lv;
        split2(v.x, hv.x, lv.x); split2(v.y, hv.y, lv.y);
        split2(v.z, hv.z, lv.z); split2(v.w, hv.w, lv.w);
        int base = r * TP + q * 8 + h * 4;
        *(ushort4*)(Ah + base) = hv;
        *(ushort4*)(Al + base) = lv;
      }
    }
    stage_bt_bf(wcos, FF, n0, 1000, k0, FF, B1h, B1l, t);
    __syncthreads();
    short8 ah[2], al[2];
#pragma unroll
    for (int i = 0; i < 2; ++i) {
      int row = (mh * 2 + i) * 16 + ln15;
      ah[i] = *(const short8*)(Ah + row * TP + q8);
      al[i] = *(const short8*)(Al + row * TP + q8);
    }
#pragma unroll
    for (int j = 0; j < 2; ++j) {
      int brow = (nh * 2 + j) * 16 + ln15;
      short8 bh = *(const short8*)(B1h + brow * TP + q8);
      short8 bl = *(const short8*)(B1l + brow * TP + q8);
#pragma unroll
      for (int i = 0; i < 2; ++i) {
        acc[i][j] = MFMA(ah[i], bh, acc[i][j]);
        acc[i][j] = MFMA(ah[i], bl, acc[i][j]);
        acc[i][j] = MFMA(al[i], bh, acc[i][j]);
      }
    }
  }
  float* logp = ws + OFF_LOGP + (size_t)ks * 64000;
#pragma unroll
  for (int i = 0; i < 2; ++i)
#pragma unroll
    for (int j = 0; j < 2; ++j) {
      int gn = n0 + (nh * 2 + j) * 16 + ln15;
      if (gn < 1000) {
#pragma unroll
        for (int r = 0; r < 4; ++r) {
          int gm = (mh * 2 + i) * 16 + lq * 4 + r;
          logp[gm * 1000 + gn] = acc[i][j][r];
        }
      }
    }
}

// ================= Kernel F: reduce 16 logit partials, apply cos-norm scales =================
__global__ __launch_bounds__(128) void kf_final(float* __restrict__ ws, float* __restrict__ out) {
  int bx = blockIdx.x, t = threadIdx.x;
  int idx0 = (bx * 128 + t) * 4;
  const float* logp = ws + OFF_LOGP + idx0;
  floatx4 s = {0.f,0.f,0.f,0.f};
#pragma unroll
  for (int ks = 0; ks < 16; ++ks)
    s += *(const floatx4*)(logp + (size_t)ks * 64000);
  floatx4 o4;
  int pb = -1;
  float sfac = 0.f;
#pragma unroll
  for (int j = 0; j < 4; ++j) {
    int idx = idx0 + j;
    int bb = idx / 1000;
    int cc = idx - bb * 1000;
    if (bb != pb) {
      float n2 = 0.f;
#pragma unroll
      for (int q = 0; q < 8; ++q) n2 += ws[OFF_NRM2P + bb * 8 + q];
      sfac = 16.f / (1.f + sqrtf(n2));
      pb = bb;
    }
    o4[j] = s[j] * sfac * ws[OFF_WINV + cc];
  }
  *(floatx4*)(out + idx0) = o4;
}

extern "C" void kernel_launch(void* const* d_in, const int* in_sizes, int n_in,
                              void* d_out, int out_size, void* d_ws, size_t ws_size,
                              hipStream_t stream) {
  const float* x     = (const float*)d_in[0];
  const float* cent  = (const float*)d_in[1];
  const float* whall = (const float*)d_in[2];
  const float* bhall = (const float*)d_in[3];
  const float* wsel  = (const float*)d_in[4];
  const float* bsel  = (const float*)d_in[5];
  const float* wcos  = (const float*)d_in[6];
  float* out = (float*)d_out;
  float* ws  = (float*)d_ws;

  hipLaunchKernelGGL(ka_gemm1,   dim3(512), dim3(256), 0, stream, x, cent, whall, wsel, wcos, ws);
  hipLaunchKernelGGL(kb_softmax, dim3(64),  dim3(256), 0, stream, bhall, ws);
  hipLaunchKernelGGL(kc_mem,     dim3(256), dim3(256), 0, stream, cent, ws);
  hipLaunchKernelGGL(kd_fuse,    dim3(512), dim3(64),  0, stream, x, bsel, ws, out);
  hipLaunchKernelGGL(ke_logits,  dim3(256), dim3(256), 0, stream, wcos, ws);
  hipLaunchKernelGGL(kf_final,   dim3(125), dim3(128), 0, stream, ws, out);
}